// Round 11
// baseline (608.618 us; speedup 1.0000x reference)
//
#include <hip/hip_runtime.h>

#define F1260 1260
#define XT_STRIDE 1344     // 7*192 floats per sample, 16B-aligned everywhere
#define XT_OFF 8192        // float offset of xT inside ws

__device__ __forceinline__ float leakyf(float x) { return x >= 0.f ? x : 0.2f * x; }
__device__ __forceinline__ float eluf(float x) { return x > 0.f ? x : expm1f(x); }
__device__ __forceinline__ float sigmoidf(float x) { return 1.f / (1.f + __expf(-x)); }
// fast tanh: exact saturation (exp->inf => 1, exp->0 => -1), ~1e-6 abs err
__device__ __forceinline__ float tanh_fast(float x) { return 1.f - 2.f / (__expf(2.f * x) + 1.f); }

// ws float layout (r10 fill-counter discovery: ws is ~660 MB):
//   0..41  : channel sums   (atomic accum, memset to 0)   42..83: sumsq
//   param block pb = ws + 128:
//       pb+0 scale[42]  pb+64 shift[42]  pb+128 adjn[7][49]
//       pb+512  WB[180][21] (stride 21 = 15.1 KB, sL1D-fits; r10 verified)
//       pb+4832 bias[84]  pb+4928 Wout[147]  pb+5078 bout[7]
//   xT at XT_OFF: [N][7][6][32] = x transposed to xT[n][v*192+c*32+tt]
//       (tt 30,31 = pad zeros) -- 176 MB, written by kA, streamed by kC.

// ---------------- kA: BN stats + transpose-write, 256 blocks x 384 thr ----------------
// Phase A (t<315): r10-exact coalesced float4 stats read -- pulls each row
// through L1. Phase B (t<336): re-reads the row from L1 (scattered, cached)
// and writes xT with coalesced float4 stores. No barriers in the loop.
__global__ __launch_bounds__(384) void kA_stats(const float* __restrict__ x,
        float* __restrict__ ws, float* __restrict__ xT, int rows, int doT) {
    __shared__ float fs[1260], fq[1260];
    const int t = threadIdx.x;
    const int n0 = blockIdx.x * rows;
    const int f0 = t * 4;                       // phase-A slot (t<315)
    // phase-B decode: out quad o=4t -> (v,c,tt0); quads never cross c/v groups
    const int o = t * 4;
    const int vb = o / 192, rb = o % 192, cb = rb >> 5, t0 = rb & 31;
    const int sbase = cb * 210 + t0 * 7 + vb;   // x offset of (cb,t0,vb)
    const bool pz = (t0 + 2) < 30, pw = (t0 + 3) < 30;

    float s0 = 0.f, s1 = 0.f, s2 = 0.f, s3 = 0.f;
    float q0 = 0.f, q1 = 0.f, q2 = 0.f, q3 = 0.f;
    for (int i = 0; i < rows; ++i) {
        const float* xr = x + (size_t)(n0 + i) * F1260;
        if (t < 315) {
            const float4 a = *(const float4*)(xr + f0);
            s0 += a.x; q0 += a.x * a.x;
            s1 += a.y; q1 += a.y * a.y;
            s2 += a.z; q2 += a.z * a.z;
            s3 += a.w; q3 += a.w * a.w;
        }
        if (doT && t < 336) {
            float4 w;
            w.x = xr[sbase];
            w.y = xr[sbase + 7];
            w.z = pz ? xr[sbase + 14] : 0.f;
            w.w = pw ? xr[sbase + 21] : 0.f;
            *(float4*)(xT + (size_t)(n0 + i) * XT_STRIDE + o) = w;
        }
    }
    if (t < 315) {
        fs[f0 + 0] = s0; fq[f0 + 0] = q0;
        fs[f0 + 1] = s1; fq[f0 + 1] = q1;
        fs[f0 + 2] = s2; fq[f0 + 2] = q2;
        fs[f0 + 3] = s3; fq[f0 + 3] = q3;
    }
    __syncthreads();
    // channel ch = v*6 + c aggregates flat f = c*210 + tt*7 + v over tt
    if (t < 42) {
        const int v = t / 6, c = t % 6;
        float s = 0.f, q = 0.f;
#pragma unroll
        for (int tt = 0; tt < 30; ++tt) {
            const int f = c * 210 + tt * 7 + v;
            s += fs[f];
            q += fq[f];
        }
        atomicAdd(&ws[t], s);
        atomicAdd(&ws[42 + t], q);
    }
}

// ---------------- kB: finalize BN, adjacency norm, weight folds ----------------
__global__ __launch_bounds__(256) void kB_setup(
        const float* __restrict__ bn_gamma, const float* __restrict__ bn_beta,
        const float* __restrict__ W1, const float* __restrict__ a1, const float* __restrict__ B1,
        const float* __restrict__ W2, const float* __restrict__ a2, const float* __restrict__ B2,
        const float* __restrict__ b_ih, const float* __restrict__ b_hh,
        const float* __restrict__ W_out, const float* __restrict__ b_out,
        float* __restrict__ ws, int N) {
    const int t = threadIdx.x;
    float* pb = ws + 128;
    const int HH[6] = {0, 3, 6, 10, 13, 16};
    const int EH[6] = {0, 3, 6, 0, 3, 6};

    // per-channel BN scale/shift from the atomic accumulators
    if (t < 42) {
        const float cnt = 30.f * (float)N;
        const float mean = ws[t] / cnt;
        const float var = ws[42 + t] / cnt - mean * mean;
        const float sc = bn_gamma[t] * rsqrtf(var + 1e-5f);
        pb[t] = sc;
        pb[64 + t] = bn_beta[t] - mean * sc;
    }
    // normalized adjacency: 6 GAT1 heads + GAT2 head0
    if (t >= 64 && t < 71) {
        const int idx = t - 64;
        const float* Bp = (idx < 6) ? (B1 + HH[idx] * 49) : B2;
        float* op = pb + 128 + idx * 49;
        float adj[49];
        for (int i = 0; i < 49; ++i) adj[i] = Bp[i];
        for (int i = 0; i < 7; ++i) adj[i * 8] += 1.f;
        float mn = adj[0], mx = adj[0];
        for (int i = 1; i < 49; ++i) { mn = fminf(mn, adj[i]); mx = fmaxf(mx, adj[i]); }
        const float inv = 1.f / (mx - mn);
        float rinv[7];
        for (int i = 0; i < 7; ++i) {
            float rs = 0.f;
            for (int j = 0; j < 7; ++j) { adj[i * 7 + j] = (adj[i * 7 + j] - mn) * inv; rs += adj[i * 7 + j]; }
            rinv[i] = rsqrtf(rs);
        }
        for (int i = 0; i < 7; ++i)
            for (int j = 0; j < 7; ++j)
                op[i * 7 + j] = adj[i * 7 + j] * rinv[i] * rinv[j];
    }
    // WB: fold a1 into W1 for the 6 live heads, repacked per-k, stride 21
    for (int task = t; task < 6 * 180; task += 256) {
        const int hh = task / 180, k = task % 180;
        const int h = HH[hh];
        const float* Wp = W1 + ((size_t)h * 180 + k) * 9;
        float si = 0.f, sj = 0.f;
        for (int e = 0; e < 9; ++e) {
            const float w = Wp[e];
            si += w * a1[h * 18 + e];
            sj += w * a1[h * 18 + 9 + e];
        }
        pb[512 + k * 21 + hh * 3 + 0] = si;
        pb[512 + k * 21 + hh * 3 + 1] = sj;
        pb[512 + k * 21 + hh * 3 + 2] = Wp[EH[hh]];
    }
    // WA2 slots (replicated per c): head 0 of l2, f=0 column kept
    if (t < 30) {
        const float* Wp = W2 + t * 10;
        float si = 0.f, sj = 0.f;
        for (int f = 0; f < 10; ++f) {
            const float w = Wp[f];
            si += w * a2[f];
            sj += w * a2[10 + f];
        }
        for (int c = 0; c < 6; ++c) {
            const int k = c * 30 + t;
            pb[512 + k * 21 + 18] = si;
            pb[512 + k * 21 + 19] = sj;
            pb[512 + k * 21 + 20] = Wp[0];
        }
    }
    if (t < 84) pb[4832 + t] = b_ih[t] + b_hh[t];
    if (t < 147) pb[4928 + t] = W_out[t];
    if (t < 7) pb[5078 + t] = b_out[t];
}

// ---------------- kC: fused dots + attention + LSTM + out ----------------
// r9/r10 structure (2-wave blocks, 16 samples, res-overlay LDS 17836 B).
// NEW: phase-1 reads the kA-written transposed copy xT with 8 aligned float4
// loads per chunk (full-line utilization, L3-resident) instead of the 30
// stride-28B scalar gather that stayed HBM-latency-bound through r4-r10
// (occupancy x2 and 3 pipelining attempts all flat). Fallback gather path
// kept for small-ws safety (doT=0).
#define RS 252
__global__ __launch_bounds__(128) void kC_main(const float* __restrict__ x,
        const float* __restrict__ xT, const float* __restrict__ pb,
        const float* __restrict__ Wih, float* __restrict__ outp, int N, int doT) {
    __shared__ __align__(16) float sm[4459];
    float* res  = sm;
    float* scsh = sm + 4032;
    float* adjL = sm + 4116;

    const int t = threadIdx.x;
    const int n0 = blockIdx.x * 16;
    const int v = (t >> 3) & 7;                // wave-local role 0..7
    const int nl = ((t >> 6) << 3) + (t & 7);  // sample row 0..15

    // ---- phase 0: params ----
    for (int i = t; i < 84; i += 128) scsh[i] = pb[i < 42 ? i : 22 + i];
    for (int i = t; i < 343; i += 128) adjL[i] = pb[128 + i];
    __syncthreads();

    // ---- phase 1: dots; thread = (v, nl), 112 active ----
    if (v < 7) {
        float s1[18];
#pragma unroll
        for (int i = 0; i < 18; ++i) s1[i] = 0.f;
        const float* WB = pb + 512;
        const float* xtb = xT + (size_t)(n0 + nl) * XT_STRIDE + v * 192;
        const float* xb  = x + (size_t)(n0 + nl) * F1260 + v;
        for (int c = 0; c < 6; ++c) {
            const float sc = scsh[v * 6 + c];
            const float sh = scsh[42 + v * 6 + c];
            const float* wb = WB + (c * 30) * 21;
            float xv[32];
            if (doT) {
                const float4* src = (const float4*)(xtb + c * 32);
#pragma unroll
                for (int k = 0; k < 8; ++k)
                    *(float4*)(xv + 4 * k) = src[k];     // aligned stream loads
            } else {
                const float* xr = xb + c * 210;
#pragma unroll
                for (int tt = 0; tt < 30; ++tt) xv[tt] = xr[tt * 7];
            }
            float g0 = 0.f, g1 = 0.f, g2 = 0.f;
#pragma unroll
            for (int tt = 0; tt < 30; ++tt) {
                const float a = xv[tt] * sc + sh;
                const float* w = wb + tt * 21;            // wave-uniform -> s_loads
#pragma unroll
                for (int q = 0; q < 18; ++q) s1[q] += a * w[q];
                g0 += a * w[18];
                g1 += a * w[19];
                g2 += a * w[20];
            }
            float* rp = res + nl * RS + 126 + (v * 6 + c) * 3;
            rp[0] = g0; rp[1] = g1; rp[2] = g2;
        }
#pragma unroll
        for (int q = 0; q < 18; ++q)
            res[nl * RS + v * 18 + q] = s1[q];
    }
    __syncthreads();

    // ---- phase 2: GAT1 heads; role hh = v ----
    // Pre-load by ALL threads (hh=6,7 read in-bounds garbage), then a barrier:
    // REQUIRED for cross-wave safety -- no overlay write may precede another
    // wave's s1 reads.
    const int hh = v;
    float si[7], sj[7], we[7];
#pragma unroll
    for (int vv = 0; vv < 7; ++vv) {
        const float* rp = res + nl * RS + vv * 18 + hh * 3;
        si[vv] = rp[0]; sj[vv] = rp[1]; we[vv] = rp[2];
    }
    __syncthreads();
    if (hh < 6) {
        float mxsj = sj[0];
#pragma unroll
        for (int j = 1; j < 7; ++j) mxsj = fmaxf(mxsj, sj[j]);
        float p[7];
#pragma unroll
        for (int i = 0; i < 7; ++i) {
            const float m = leakyf(si[i] + mxsj);   // leaky monotonic -> row max
            float den = 0.f, num = 0.f;
#pragma unroll
            for (int j = 0; j < 7; ++j) {
                const float w = __expf(leakyf(si[i] + sj[j]) - m);
                den += w;
                num += w * we[j];
            }
            p[i] = num / den;
        }
        const float* An = adjL + hh * 49;
#pragma unroll
        for (int i = 0; i < 7; ++i) {
            float r = 0.f;
#pragma unroll
            for (int k = 0; k < 7; ++k) r += An[i * 7 + k] * p[k];
            res[nl * RS + hh * 7 + i] = eluf(r);        // xs0 overlay [0..42)
        }
    }
    // ---- phase 2b: GAT2 softmax-over-channels; role i = v (<7) ----
    // reads g [126..252) of own row, writes h2t overlay [84..126) -- disjoint
    if (v < 7) {
        const int i = v;
        float si2[6];
#pragma unroll
        for (int c = 0; c < 6; ++c)
            si2[c] = res[nl * RS + 126 + (i * 6 + c) * 3];
        float hc[6];
#pragma unroll
        for (int c = 0; c < 6; ++c) hc[c] = 0.f;
#pragma unroll
        for (int j = 0; j < 7; ++j) {
            float s[6];
            float m = -1e30f;
#pragma unroll
            for (int c = 0; c < 6; ++c) {
                const float* rp = res + nl * RS + 126 + (j * 6 + c) * 3;
                s[c] = leakyf(si2[c] + rp[1]);
                m = fmaxf(m, s[c]);
            }
            float den = 0.f;
#pragma unroll
            for (int c = 0; c < 6; ++c) { s[c] = __expf(s[c] - m); den += s[c]; }
            const float rd = 1.f / den;
#pragma unroll
            for (int c = 0; c < 6; ++c) {
                const float wh0 = res[nl * RS + 126 + (j * 6 + c) * 3 + 2];
                hc[c] += wh0 * s[c] * rd;
            }
        }
#pragma unroll
        for (int c = 0; c < 6; ++c)
            res[nl * RS + 84 + i * 6 + c] = hc[c];      // h2t overlay [84..126)
    }
    __syncthreads();

    // ---- phase 3: GAT2 adj multiply; role c = v (<6) ----
    // reads h2t [84..126) of own row, writes xs0 [42..84) -- disjoint
    if (v < 6) {
        const int c = v;
        const float* An2 = adjL + 6 * 49;
        float h[7];
#pragma unroll
        for (int u = 0; u < 7; ++u) h[u] = res[nl * RS + 84 + u * 6 + c];
#pragma unroll
        for (int vv = 0; vv < 7; ++vv) {
            float r = 0.f;
#pragma unroll
            for (int u = 0; u < 7; ++u) r += h[u] * An2[u * 7 + vv];
            res[nl * RS + 42 + c * 7 + vv] = eluf(r);   // xs0 overlay [42..84)
        }
    }
    __syncthreads();

    // ---- phase 4: LSTM step 0; role g8 = v, all threads; float4 reads ----
    // reads xs0 [0..84) (row base 1008B-aligned), writes h1s overlay [126..148)
    {
        const int g8 = v;
        const float* bias = pb + 4832;
        const float4* xs4 = (const float4*)(res + nl * RS);
        for (int gi = g8; gi < 21; gi += 8) {
            float ga = bias[gi], gg = bias[42 + gi], go = bias[63 + gi];
            const float4* wa = (const float4*)(Wih + gi * 84);
            const float4* wg = (const float4*)(Wih + (42 + gi) * 84);
            const float4* wo = (const float4*)(Wih + (63 + gi) * 84);
#pragma unroll
            for (int k = 0; k < 21; ++k) {
                const float4 xv = xs4[k];
                const float4 a4 = wa[k];
                const float4 g4 = wg[k];
                const float4 o4 = wo[k];
                ga += xv.x * a4.x + xv.y * a4.y + xv.z * a4.z + xv.w * a4.w;
                gg += xv.x * g4.x + xv.y * g4.y + xv.z * g4.z + xv.w * g4.w;
                go += xv.x * o4.x + xv.y * o4.y + xv.z * o4.z + xv.w * o4.w;
            }
            const float c1 = sigmoidf(ga) * tanh_fast(gg);
            res[nl * RS + 126 + gi] = sigmoidf(go) * tanh_fast(c1);
        }
    }
    __syncthreads();

    // ---- phase 5: output projection; thread = n5*7+j, 112 active, coalesced ----
    if (t < 112) {
        const int n5 = t / 7, j = t - n5 * 7;
        const float* Wout = pb + 4928;
        float r = pb[5078 + j];
#pragma unroll
        for (int m = 0; m < 21; ++m) r += res[n5 * RS + 126 + m] * Wout[j * 21 + m];
        outp[(size_t)n0 * 7 + t] = r;
    }
}

extern "C" void kernel_launch(void* const* d_in, const int* in_sizes, int n_in,
                              void* d_out, int out_size, void* d_ws, size_t ws_size,
                              hipStream_t stream) {
    const int N = in_sizes[0] / F1260;

    const float* x        = (const float*)d_in[0];
    const float* bn_gamma = (const float*)d_in[1];
    const float* bn_beta  = (const float*)d_in[2];
    const float* W1       = (const float*)d_in[3];
    const float* a1       = (const float*)d_in[4];
    const float* B1       = (const float*)d_in[5];
    const float* W2       = (const float*)d_in[6];
    const float* a2       = (const float*)d_in[7];
    const float* B2       = (const float*)d_in[8];
    const float* W_ih     = (const float*)d_in[9];
    // d_in[10] = W_hh unused (h0 = 0 -> only LSTM step 0 matters)
    const float* b_ih     = (const float*)d_in[11];
    const float* b_hh     = (const float*)d_in[12];
    const float* W_out    = (const float*)d_in[13];
    const float* b_out    = (const float*)d_in[14];

    float* wsf = (float*)d_ws;

    // transposed-copy path needs 32 KB + N*1344*4 B (176 MB at N=32768);
    // r10 fill counters show ws ~660 MB, but guard anyway.
    const int doT = (ws_size >= (size_t)(XT_OFF + (size_t)N * XT_STRIDE) * sizeof(float)) ? 1 : 0;
    float* xT = wsf + XT_OFF;

    hipMemsetAsync(d_ws, 0, 128 * sizeof(float), stream);   // zero channel accums

    kA_stats<<<dim3(256), dim3(384), 0, stream>>>(x, wsf, xT, N / 256, doT);
    kB_setup<<<dim3(1), dim3(256), 0, stream>>>(bn_gamma, bn_beta, W1, a1, B1,
                                                W2, a2, B2, b_ih, b_hh,
                                                W_out, b_out, wsf, N);
    kC_main<<<dim3(N / 16), dim3(128), 0, stream>>>(x, xT, wsf + 128, W_ih,
                                                    (float*)d_out, N, doT);
}

// Round 12
// 340.976 us; speedup vs baseline: 1.7849x; 1.7849x over previous
//
#include <hip/hip_runtime.h>

#define F1260 1260
#define NPART 512                 // kA blocks (2/CU); plain-store partial slots
#define PB_OFF (NPART * 84)       // param block float offset (43008)

__device__ __forceinline__ float leakyf(float x) { return x >= 0.f ? x : 0.2f * x; }
__device__ __forceinline__ float eluf(float x) { return x > 0.f ? x : expm1f(x); }
__device__ __forceinline__ float sigmoidf(float x) { return 1.f / (1.f + __expf(-x)); }
// fast tanh: exact saturation (exp->inf => 1, exp->0 => -1), ~1e-6 abs err
__device__ __forceinline__ float tanh_fast(float x) { return 1.f - 2.f / (__expf(2.f * x) + 1.f); }

// ws float layout:
//   0 .. NPART*84 : per-block channel partials (b*84+ch = sum, b*84+42+ch = sq),
//                   plain stores (no atomics, no memset needed)
//   param block pb = ws + PB_OFF:
//       pb+0 scale[42]  pb+64 shift[42]  pb+128 adjn[7][49]
//       pb+512  WB[180][21] (stride 21 = 15.1 KB, sL1D-fits; r10-verified kC win)
//       pb+4832 bias[84]  pb+4928 Wout[147]  pb+5078 bout[7]
// r11 lesson: do NOT build large ws-resident copies of x -- kC's gather wins
// precisely because kA's read leaves x half-resident in L3 (kC FETCH 84 MB of
// a 165 MB input); the xT copy made kC stream 330 MB cold (232 us).

// ---------------- kA: BN stats, float4-coalesced, 512 blocks ----------------
// Same r5/r9 body; 512 blocks x 320 thr x 64 rows = 2 blocks/CU, 10 waves/CU
// (the streaming-ubench occupancy regime). Plain stores to 512 slots; the
// r10 atomic tail (84 addr x 256-deep) is removed.
__global__ __launch_bounds__(320) void kA_stats(const float* __restrict__ x,
                                                float* __restrict__ ws, int rows) {
    __shared__ float fs[1260], fq[1260];
    const int t = threadIdx.x;
    const int n0 = blockIdx.x * rows;
    if (t < 315) {
        const int f0 = t * 4;
        float s0 = 0.f, s1 = 0.f, s2 = 0.f, s3 = 0.f;
        float q0 = 0.f, q1 = 0.f, q2 = 0.f, q3 = 0.f;
#pragma unroll 16
        for (int i = 0; i < rows; ++i) {
            const float4 a = *(const float4*)(x + (size_t)(n0 + i) * F1260 + f0);
            s0 += a.x; q0 += a.x * a.x;
            s1 += a.y; q1 += a.y * a.y;
            s2 += a.z; q2 += a.z * a.z;
            s3 += a.w; q3 += a.w * a.w;
        }
        fs[f0 + 0] = s0; fq[f0 + 0] = q0;
        fs[f0 + 1] = s1; fq[f0 + 1] = q1;
        fs[f0 + 2] = s2; fq[f0 + 2] = q2;
        fs[f0 + 3] = s3; fq[f0 + 3] = q3;
    }
    __syncthreads();
    // channel ch = v*6 + c aggregates flat f = c*210 + tt*7 + v over tt
    if (t < 42) {
        const int v = t / 6, c = t % 6;
        float s = 0.f, q = 0.f;
#pragma unroll
        for (int tt = 0; tt < 30; ++tt) {
            const int f = c * 210 + tt * 7 + v;
            s += fs[f];
            q += fq[f];
        }
        ws[blockIdx.x * 84 + t] = s;
        ws[blockIdx.x * 84 + 42 + t] = q;
    }
}

// ---------------- kB: finalize BN, adjacency norm, weight folds ----------------
// 384 threads; stats reduce parallelized 4-way (part x 84 slots) so the
// 512-slot partial sum doesn't become a serial tail.
__global__ __launch_bounds__(384) void kB_setup(
        const float* __restrict__ bn_gamma, const float* __restrict__ bn_beta,
        const float* __restrict__ W1, const float* __restrict__ a1, const float* __restrict__ B1,
        const float* __restrict__ W2, const float* __restrict__ a2, const float* __restrict__ B2,
        const float* __restrict__ b_ih, const float* __restrict__ b_hh,
        const float* __restrict__ W_out, const float* __restrict__ b_out,
        float* __restrict__ ws, int N) {
    __shared__ float red[336];
    const int t = threadIdx.x;
    float* pb = ws + PB_OFF;
    const int HH[6] = {0, 3, 6, 10, 13, 16};
    const int EH[6] = {0, 3, 6, 0, 3, 6};

    // stage 1: 336 threads = part(0..3) x slot(0..83); each sums 128 blocks
    if (t < 336) {
        const int part = t / 84, slot = t - part * 84;
        const int b0 = part * (NPART / 4);
        float s = 0.f;
#pragma unroll 8
        for (int b = 0; b < NPART / 4; ++b) s += ws[(size_t)(b0 + b) * 84 + slot];
        red[t] = s;
    }
    __syncthreads();
    // stage 2: finalize per-channel BN scale/shift
    if (t < 42) {
        const float s = red[t] + red[84 + t] + red[168 + t] + red[252 + t];
        const float q = red[42 + t] + red[126 + t] + red[210 + t] + red[294 + t];
        const float cnt = 30.f * (float)N;
        const float mean = s / cnt;
        const float var = q / cnt - mean * mean;
        const float sc = bn_gamma[t] * rsqrtf(var + 1e-5f);
        pb[t] = sc;
        pb[64 + t] = bn_beta[t] - mean * sc;
    }
    // normalized adjacency: 6 GAT1 heads + GAT2 head0
    if (t >= 64 && t < 71) {
        const int idx = t - 64;
        const float* Bp = (idx < 6) ? (B1 + HH[idx] * 49) : B2;
        float* op = pb + 128 + idx * 49;
        float adj[49];
        for (int i = 0; i < 49; ++i) adj[i] = Bp[i];
        for (int i = 0; i < 7; ++i) adj[i * 8] += 1.f;
        float mn = adj[0], mx = adj[0];
        for (int i = 1; i < 49; ++i) { mn = fminf(mn, adj[i]); mx = fmaxf(mx, adj[i]); }
        const float inv = 1.f / (mx - mn);
        float rinv[7];
        for (int i = 0; i < 7; ++i) {
            float rs = 0.f;
            for (int j = 0; j < 7; ++j) { adj[i * 7 + j] = (adj[i * 7 + j] - mn) * inv; rs += adj[i * 7 + j]; }
            rinv[i] = rsqrtf(rs);
        }
        for (int i = 0; i < 7; ++i)
            for (int j = 0; j < 7; ++j)
                op[i * 7 + j] = adj[i * 7 + j] * rinv[i] * rinv[j];
    }
    // WB: fold a1 into W1 for the 6 live heads, repacked per-k, stride 21
    for (int task = t; task < 6 * 180; task += 384) {
        const int hh = task / 180, k = task % 180;
        const int h = HH[hh];
        const float* Wp = W1 + ((size_t)h * 180 + k) * 9;
        float si = 0.f, sj = 0.f;
        for (int e = 0; e < 9; ++e) {
            const float w = Wp[e];
            si += w * a1[h * 18 + e];
            sj += w * a1[h * 18 + 9 + e];
        }
        pb[512 + k * 21 + hh * 3 + 0] = si;
        pb[512 + k * 21 + hh * 3 + 1] = sj;
        pb[512 + k * 21 + hh * 3 + 2] = Wp[EH[hh]];
    }
    // WA2 slots (replicated per c): head 0 of l2, f=0 column kept
    if (t < 30) {
        const float* Wp = W2 + t * 10;
        float si = 0.f, sj = 0.f;
        for (int f = 0; f < 10; ++f) {
            const float w = Wp[f];
            si += w * a2[f];
            sj += w * a2[10 + f];
        }
        for (int c = 0; c < 6; ++c) {
            const int k = c * 30 + t;
            pb[512 + k * 21 + 18] = si;
            pb[512 + k * 21 + 19] = sj;
            pb[512 + k * 21 + 20] = Wp[0];
        }
    }
    if (t < 84) pb[4832 + t] = b_ih[t] + b_hh[t];
    if (t < 147) pb[4928 + t] = W_out[t];
    if (t < 7) pb[5078 + t] = b_out[t];
}

// ---------------- kC: fused dots + attention + LSTM + out ----------------
// r10-exact (best measured: below the 94 us fill cutoff). 2-wave blocks
// (128 threads, 16 samples), wave-local roles, res-overlay LDS (17836 B),
// WB stride 21 (sL1D fit), direct stride-7 gather of x (L3-half-resident
// from kA's read -- r11 proved staging a transposed copy is strictly worse).
#define RS 252
__global__ __launch_bounds__(128) void kC_main(const float* __restrict__ x,
        const float* __restrict__ pb, const float* __restrict__ Wih,
        float* __restrict__ outp, int N) {
    __shared__ __align__(16) float sm[4459];
    float* res  = sm;
    float* scsh = sm + 4032;
    float* adjL = sm + 4116;

    const int t = threadIdx.x;
    const int n0 = blockIdx.x * 16;
    const int v = (t >> 3) & 7;                // wave-local role 0..7
    const int nl = ((t >> 6) << 3) + (t & 7);  // sample row 0..15

    // ---- phase 0: params ----
    for (int i = t; i < 84; i += 128) scsh[i] = pb[i < 42 ? i : 22 + i];
    for (int i = t; i < 343; i += 128) adjL[i] = pb[128 + i];
    __syncthreads();

    // ---- phase 1: dots; thread = (v, nl), 112 active ----
    if (v < 7) {
        float s1[18];
#pragma unroll
        for (int i = 0; i < 18; ++i) s1[i] = 0.f;
        const float* xb = x + (size_t)(n0 + nl) * F1260 + v;
        const float* WB = pb + 512;
        for (int c = 0; c < 6; ++c) {
            const float sc = scsh[v * 6 + c];
            const float sh = scsh[42 + v * 6 + c];
            const float* xr = xb + c * 210;
            const float* wb = WB + (c * 30) * 21;
            float xv[30];
#pragma unroll
            for (int tt = 0; tt < 30; ++tt) xv[tt] = xr[tt * 7];   // batch loads
            float g0 = 0.f, g1 = 0.f, g2 = 0.f;
#pragma unroll
            for (int tt = 0; tt < 30; ++tt) {
                const float a = xv[tt] * sc + sh;
                const float* w = wb + tt * 21;                      // wave-uniform -> s_loads
#pragma unroll
                for (int q = 0; q < 18; ++q) s1[q] += a * w[q];
                g0 += a * w[18];
                g1 += a * w[19];
                g2 += a * w[20];
            }
            float* rp = res + nl * RS + 126 + (v * 6 + c) * 3;
            rp[0] = g0; rp[1] = g1; rp[2] = g2;
        }
#pragma unroll
        for (int q = 0; q < 18; ++q)
            res[nl * RS + v * 18 + q] = s1[q];
    }
    __syncthreads();

    // ---- phase 2: GAT1 heads; role hh = v ----
    // Pre-load by ALL threads (hh=6,7 read in-bounds garbage), then a barrier:
    // REQUIRED for cross-wave safety -- no overlay write may precede another
    // wave's s1 reads.
    const int hh = v;
    float si[7], sj[7], we[7];
#pragma unroll
    for (int vv = 0; vv < 7; ++vv) {
        const float* rp = res + nl * RS + vv * 18 + hh * 3;
        si[vv] = rp[0]; sj[vv] = rp[1]; we[vv] = rp[2];
    }
    __syncthreads();
    if (hh < 6) {
        float mxsj = sj[0];
#pragma unroll
        for (int j = 1; j < 7; ++j) mxsj = fmaxf(mxsj, sj[j]);
        float p[7];
#pragma unroll
        for (int i = 0; i < 7; ++i) {
            const float m = leakyf(si[i] + mxsj);   // leaky monotonic -> row max
            float den = 0.f, num = 0.f;
#pragma unroll
            for (int j = 0; j < 7; ++j) {
                const float w = __expf(leakyf(si[i] + sj[j]) - m);
                den += w;
                num += w * we[j];
            }
            p[i] = num / den;
        }
        const float* An = adjL + hh * 49;
#pragma unroll
        for (int i = 0; i < 7; ++i) {
            float r = 0.f;
#pragma unroll
            for (int k = 0; k < 7; ++k) r += An[i * 7 + k] * p[k];
            res[nl * RS + hh * 7 + i] = eluf(r);        // xs0 overlay [0..42)
        }
    }
    // ---- phase 2b: GAT2 softmax-over-channels; role i = v (<7) ----
    // reads g [126..252) of own row, writes h2t overlay [84..126) -- disjoint
    if (v < 7) {
        const int i = v;
        float si2[6];
#pragma unroll
        for (int c = 0; c < 6; ++c)
            si2[c] = res[nl * RS + 126 + (i * 6 + c) * 3];
        float hc[6];
#pragma unroll
        for (int c = 0; c < 6; ++c) hc[c] = 0.f;
#pragma unroll
        for (int j = 0; j < 7; ++j) {
            float s[6];
            float m = -1e30f;
#pragma unroll
            for (int c = 0; c < 6; ++c) {
                const float* rp = res + nl * RS + 126 + (j * 6 + c) * 3;
                s[c] = leakyf(si2[c] + rp[1]);
                m = fmaxf(m, s[c]);
            }
            float den = 0.f;
#pragma unroll
            for (int c = 0; c < 6; ++c) { s[c] = __expf(s[c] - m); den += s[c]; }
            const float rd = 1.f / den;
#pragma unroll
            for (int c = 0; c < 6; ++c) {
                const float wh0 = res[nl * RS + 126 + (j * 6 + c) * 3 + 2];
                hc[c] += wh0 * s[c] * rd;
            }
        }
#pragma unroll
        for (int c = 0; c < 6; ++c)
            res[nl * RS + 84 + i * 6 + c] = hc[c];      // h2t overlay [84..126)
    }
    __syncthreads();

    // ---- phase 3: GAT2 adj multiply; role c = v (<6) ----
    // reads h2t [84..126) of own row, writes xs0 [42..84) -- disjoint
    if (v < 6) {
        const int c = v;
        const float* An2 = adjL + 6 * 49;
        float h[7];
#pragma unroll
        for (int u = 0; u < 7; ++u) h[u] = res[nl * RS + 84 + u * 6 + c];
#pragma unroll
        for (int vv = 0; vv < 7; ++vv) {
            float r = 0.f;
#pragma unroll
            for (int u = 0; u < 7; ++u) r += h[u] * An2[u * 7 + vv];
            res[nl * RS + 42 + c * 7 + vv] = eluf(r);   // xs0 overlay [42..84)
        }
    }
    __syncthreads();

    // ---- phase 4: LSTM step 0; role g8 = v, all threads; float4 reads ----
    // reads xs0 [0..84) (row base 1008B-aligned), writes h1s overlay [126..148)
    {
        const int g8 = v;
        const float* bias = pb + 4832;
        const float4* xs4 = (const float4*)(res + nl * RS);
        for (int gi = g8; gi < 21; gi += 8) {
            float ga = bias[gi], gg = bias[42 + gi], go = bias[63 + gi];
            const float4* wa = (const float4*)(Wih + gi * 84);
            const float4* wg = (const float4*)(Wih + (42 + gi) * 84);
            const float4* wo = (const float4*)(Wih + (63 + gi) * 84);
#pragma unroll
            for (int k = 0; k < 21; ++k) {
                const float4 xv = xs4[k];
                const float4 a4 = wa[k];
                const float4 g4 = wg[k];
                const float4 o4 = wo[k];
                ga += xv.x * a4.x + xv.y * a4.y + xv.z * a4.z + xv.w * a4.w;
                gg += xv.x * g4.x + xv.y * g4.y + xv.z * g4.z + xv.w * g4.w;
                go += xv.x * o4.x + xv.y * o4.y + xv.z * o4.z + xv.w * o4.w;
            }
            const float c1 = sigmoidf(ga) * tanh_fast(gg);
            res[nl * RS + 126 + gi] = sigmoidf(go) * tanh_fast(c1);
        }
    }
    __syncthreads();

    // ---- phase 5: output projection; thread = n5*7+j, 112 active, coalesced ----
    if (t < 112) {
        const int n5 = t / 7, j = t - n5 * 7;
        const float* Wout = pb + 4928;
        float r = pb[5078 + j];
#pragma unroll
        for (int m = 0; m < 21; ++m) r += res[n5 * RS + 126 + m] * Wout[j * 21 + m];
        outp[(size_t)n0 * 7 + t] = r;
    }
}

extern "C" void kernel_launch(void* const* d_in, const int* in_sizes, int n_in,
                              void* d_out, int out_size, void* d_ws, size_t ws_size,
                              hipStream_t stream) {
    const int N = in_sizes[0] / F1260;

    const float* x        = (const float*)d_in[0];
    const float* bn_gamma = (const float*)d_in[1];
    const float* bn_beta  = (const float*)d_in[2];
    const float* W1       = (const float*)d_in[3];
    const float* a1       = (const float*)d_in[4];
    const float* B1       = (const float*)d_in[5];
    const float* W2       = (const float*)d_in[6];
    const float* a2       = (const float*)d_in[7];
    const float* B2       = (const float*)d_in[8];
    const float* W_ih     = (const float*)d_in[9];
    // d_in[10] = W_hh unused (h0 = 0 -> only LSTM step 0 matters)
    const float* b_ih     = (const float*)d_in[11];
    const float* b_hh     = (const float*)d_in[12];
    const float* W_out    = (const float*)d_in[13];
    const float* b_out    = (const float*)d_in[14];

    float* wsf = (float*)d_ws;

    // no memset dispatch: kA writes its partials with plain stores

    kA_stats<<<dim3(NPART), dim3(320), 0, stream>>>(x, wsf, N / NPART);
    kB_setup<<<dim3(1), dim3(384), 0, stream>>>(bn_gamma, bn_beta, W1, a1, B1,
                                                W2, a2, B2, b_ih, b_hh,
                                                W_out, b_out, wsf, N);
    kC_main<<<dim3(N / 16), dim3(128), 0, stream>>>(x, wsf + PB_OFF, W_ih,
                                                    (float*)d_out, N);
}